// Round 11
// baseline (265.423 us; speedup 1.0000x reference)
//
#include <hip/hip_runtime.h>
#include <stdint.h>

#define NN 50000
#define EE 600000
#define INF 256
#define HF 128
#define CEB ((EE + 255) / 256)    // 2344 edge blocks
#define GBT ((NN + 63) / 64)      // 782 gemm tiles
#define NBCH ((NN + 255) / 256)   // 196 scan chunks
#define NLB 8                     // count privatization labels (XCD count)

typedef __attribute__((ext_vector_type(8))) short short8;
typedef __attribute__((ext_vector_type(4))) float floatx4;

// ---------------- bf16 helpers ----------------
__device__ __forceinline__ unsigned short f32_to_bf16_rne(float x) {
    unsigned int u = __float_as_uint(x);
    unsigned int r = (u + 0x7FFFu + ((u >> 16) & 1u)) >> 16;
    return (unsigned short)r;
}
__device__ __forceinline__ float bf16_to_f32(unsigned short h) {
    return __uint_as_float(((unsigned int)h) << 16);
}
__device__ __forceinline__ float bf16lo_u32(unsigned int u) {
    return __uint_as_float(u << 16);
}
__device__ __forceinline__ float bf16hi_u32(unsigned int u) {
    return __uint_as_float(u & 0xFFFF0000u);
}
__device__ __forceinline__ void cvt_hilo8(float4 v0, float4 v1, short8& hs, short8& ls) {
    float x[8] = {v0.x, v0.y, v0.z, v0.w, v1.x, v1.y, v1.z, v1.w};
    union { short8 s; unsigned short u[8]; } H, L;
#pragma unroll
    for (int k = 0; k < 8; ++k) {
        unsigned short hi = f32_to_bf16_rne(x[k]);
        H.u[k] = hi;
        L.u[k] = f32_to_bf16_rne(x[k] - bf16_to_f32(hi));
    }
    hs = H.s;
    ls = L.s;
}

// ---------------- weight prepack: f32 -> hi/lo bf16 fragment-linear layout ----------
// linear order == LDS staging order, so GEMM staging is a pure 16B async copy.
__device__ __forceinline__ void prepack_one(int idx, const float* lw, const float* cw,
                                            unsigned short* fl, unsigned short* fc) {
    const float* src; unsigned short* dst; int K, c;
    if (idx < 8192) { src = lw; dst = fl; K = INF; c = idx; }
    else            { src = cw; dst = fc; K = HF; c = idx - 8192; }
    int lane = c & 63;
    int nt = (c >> 6) & 7;
    int hl = (c >> 9) & 1;
    int kc = c >> 10;
    int rw = nt * 16 + (lane & 15);
    int koff = kc * 32 + (lane >> 4) * 8;
    const float* p = &src[(size_t)rw * K + koff];
    float4 v0 = *reinterpret_cast<const float4*>(p);
    float4 v1 = *reinterpret_cast<const float4*>(p + 4);
    short8 hs, ls;
    cvt_hilo8(v0, v1, hs, ls);
    *reinterpret_cast<short8*>(&dst[(size_t)c * 8]) = hl ? ls : hs;
}

// ---------------- L1: zero cnt8 + prepack both weight matrices ----------------
__global__ void zero_prepack(const float* __restrict__ lw, const float* __restrict__ cw,
                             unsigned short* __restrict__ fl, unsigned short* __restrict__ fc,
                             int* __restrict__ cnt8) {
    int g = blockIdx.x * 256 + threadIdx.x;
    if (g < 12288) prepack_one(g, lw, cw, fl, fc);
    for (int i = g; i < NLB * NN; i += 256 * 256) cnt8[i] = 0;
}

// ---------------- scan phase1: per-chunk sums of deg (deg = sum over 8 labels) ------
__global__ void scan_phase1(const int* __restrict__ cnt8, int* __restrict__ bsum, int n) {
    __shared__ int sdata[256];
    int t = threadIdx.x;
    int i = blockIdx.x * 256 + t;
    int d = 0;
    if (i < n) {
#pragma unroll
        for (int k = 0; k < NLB; ++k) d += cnt8[(size_t)k * NN + i];
    }
    sdata[t] = d;
    __syncthreads();
    for (int s = 128; s > 0; s >>= 1) {
        if (t < s) sdata[t] += sdata[t + s];
        __syncthreads();
    }
    if (t == 0) bsum[blockIdx.x] = sdata[0];
}

// ---------------- scan phase2+3: row_start + per-label bases (in-place) + deg funcs --
__global__ void scan_phase3(int* __restrict__ cnt8, const int* __restrict__ bsum,
                            int* __restrict__ row_start,
                            float* __restrict__ deg_inv, float* __restrict__ dis,
                            int n, int nb, int E) {
    __shared__ int sb[256];
    __shared__ int sdata[256];
    int t = threadIdx.x;
    sb[t] = (t < nb) ? bsum[t] : 0;
    __syncthreads();
    for (int s = 1; s < 256; s <<= 1) {
        int add = (t >= s) ? sb[t - s] : 0;
        __syncthreads();
        sb[t] += add;
        __syncthreads();
    }
    int base = sb[blockIdx.x] - bsum[blockIdx.x];
    int i = blockIdx.x * 256 + t;
    int c8[NLB];
    int v = 0;
    if (i < n) {
#pragma unroll
        for (int k = 0; k < NLB; ++k) {
            c8[k] = cnt8[(size_t)k * NN + i];
            v += c8[k];
        }
    }
    sdata[t] = v;
    __syncthreads();
    for (int s = 1; s < 256; s <<= 1) {
        int add = (t >= s) ? sdata[t - s] : 0;
        __syncthreads();
        sdata[t] += add;
        __syncthreads();
    }
    if (i < n) {
        int rs = base + sdata[t] - v;
        row_start[i] = rs;
        int acc = rs;
#pragma unroll
        for (int k = 0; k < NLB; ++k) {   // rewrite counts -> per-label slot bases
            int cc = c8[k];
            cnt8[(size_t)k * NN + i] = acc;
            acc += cc;
        }
        float d = (float)(v + 1);
        deg_inv[i] = 1.0f / d;
        dis[i] = rsqrtf(d);
    }
    if (blockIdx.x == 0 && t == 0) row_start[n] = E;
}

// ---------------- split-bf16 MFMA GEMM tile; W staged by linear async copy ---------
// A always f32 (cvt in-loop). MODE 0: +bias -> f32 C.
// MODE 1: scale by Dis[row], hi/lo bf16 split C (xws = dis*xw convention).
template <int K, int MODE>
__device__ __forceinline__ void gemm_tile(
    int bidx, const float* __restrict__ Af, const unsigned short* __restrict__ Wf,
    const float* __restrict__ bias, const float* __restrict__ Dis,
    float* __restrict__ Cf,
    unsigned short* __restrict__ Chi, unsigned short* __restrict__ Clo,
    unsigned short* WS, int M) {
    constexpr int NKC = K / 32;
    const int t = threadIdx.x;
    const int wave = t >> 6;
    const int lane = t & 63;
    const int lrow = lane & 15;
    const int quad = lane >> 4;
    const int bm = bidx * 64;
    int arow = bm + wave * 16 + lrow;
    if (arow >= M) arow = M - 1;   // clamp; stores are predicated

    floatx4 acc[8];
#pragma unroll
    for (int nt = 0; nt < 8; ++nt) acc[nt] = (floatx4){0.f, 0.f, 0.f, 0.f};

#pragma unroll
    for (int pp = 0; pp < NKC / 2; ++pp) {
        if (pp) __syncthreads();
        {
            const unsigned short* src = Wf + (size_t)pp * 16384 + (size_t)t * 8;
#if __has_builtin(__builtin_amdgcn_global_load_lds)
#pragma unroll
            for (int i = 0; i < 8; ++i) {
                __builtin_amdgcn_global_load_lds(
                    (const unsigned int*)(src + (size_t)i * 2048),
                    (unsigned int*)(WS + ((size_t)i * 256 + (t >> 6) * 64) * 8),
                    16, 0, 0);
            }
#else
            const uint4* s4 = reinterpret_cast<const uint4*>(Wf + (size_t)pp * 16384);
            uint4* d4 = reinterpret_cast<uint4*>(WS);
#pragma unroll
            for (int i = 0; i < 8; ++i) d4[t + 256 * i] = s4[t + 256 * i];
#endif
        }
        __syncthreads();
#pragma unroll
        for (int k2 = 0; k2 < 2; ++k2) {
            int kc = pp * 2 + k2;
            const float* ap = &Af[(size_t)arow * K + kc * 32 + quad * 8];
            float4 a0 = *reinterpret_cast<const float4*>(ap);
            float4 a1 = *reinterpret_cast<const float4*>(ap + 4);
            short8 afh, afl;
            cvt_hilo8(a0, a1, afh, afl);
            const unsigned short* wb = &WS[k2 * 8192 + lane * 8];
#pragma unroll
            for (int nt = 0; nt < 8; ++nt) {
                short8 bfh = *reinterpret_cast<const short8*>(wb + nt * 512);
                short8 bfl = *reinterpret_cast<const short8*>(wb + 4096 + nt * 512);
                acc[nt] = __builtin_amdgcn_mfma_f32_16x16x32_bf16(afh, bfh, acc[nt], 0, 0, 0);
                acc[nt] = __builtin_amdgcn_mfma_f32_16x16x32_bf16(afl, bfh, acc[nt], 0, 0, 0);
                acc[nt] = __builtin_amdgcn_mfma_f32_16x16x32_bf16(afh, bfl, acc[nt], 0, 0, 0);
            }
        }
    }

    float cb[8];
    if (MODE == 0) {
#pragma unroll
        for (int nt = 0; nt < 8; ++nt) cb[nt] = bias[nt * 16 + lrow];
    }

#pragma unroll
    for (int r = 0; r < 4; ++r) {
        int grow = bm + wave * 16 + quad * 4 + r;
        if (grow >= M) continue;
        float dsr = (MODE == 1) ? Dis[grow] : 0.f;
#pragma unroll
        for (int nt = 0; nt < 8; ++nt) {
            int colh = nt * 16 + lrow;
            if (MODE == 0) {
                Cf[(size_t)grow * HF + colh] = acc[nt][r] + cb[nt];
            } else {
                float x = acc[nt][r] * dsr;   // pre-scale by dis[row]
                unsigned short hi = f32_to_bf16_rne(x);
                Chi[(size_t)grow * HF + colh] = hi;
                Clo[(size_t)grow * HF + colh] = f32_to_bf16_rne(x - bf16_to_f32(hi));
            }
        }
    }
}

// ---------------- L2: gemm0 ∥ privatized degree count ----------------
__global__ __launch_bounds__(256) void gemm0_count(
    const float* __restrict__ in_feat, const unsigned short* __restrict__ fl,
    const float* __restrict__ lin_b, float* __restrict__ h0,
    const int* __restrict__ row, int* __restrict__ cnt8, int* __restrict__ pos) {
    __shared__ unsigned short WS[2 * 8192];
    int b = blockIdx.x;
    if (b < GBT) {
        gemm_tile<INF, 0>(b, in_feat, fl, lin_b, nullptr, h0, nullptr, nullptr, WS, NN);
        return;
    }
    int eb = b - GBT;
    int e = eb * 256 + threadIdx.x;
    if (e < EE) pos[e] = atomicAdd(&cnt8[(size_t)(eb & 7) * NN + row[e]], 1);
}

// ---------------- L4: xws0 = dis*(h0 @ conv_w^T) (split write) ∥ CSR fill ----------
__global__ __launch_bounds__(256) void xw_fill(
    const float* __restrict__ h, const unsigned short* __restrict__ fc,
    const float* __restrict__ dis,
    unsigned short* __restrict__ xw_hi, unsigned short* __restrict__ xw_lo,
    const int* __restrict__ row, const int* __restrict__ col,
    const int* __restrict__ cnt8_base, const int* __restrict__ pos,
    int* __restrict__ csr_col) {
    __shared__ unsigned short WS[2 * 8192];
    int b = blockIdx.x;
    if (b < GBT) {
        gemm_tile<HF, 1>(b, h, fc, nullptr, dis, nullptr, xw_hi, xw_lo, WS, NN);
        return;
    }
    int eb = b - GBT;
    int e = eb * 256 + threadIdx.x;
    if (e < EE) {
        int p = cnt8_base[(size_t)(eb & 7) * NN + row[e]] + pos[e];
        __builtin_nontemporal_store(col[e], &csr_col[p]);
    }
}

// ---------------- L6: xws1 = dis*(h1 @ conv_w^T) (split write) ----------------
__global__ __launch_bounds__(256) void xw_only(
    const float* __restrict__ h, const unsigned short* __restrict__ fc,
    const float* __restrict__ dis,
    unsigned short* __restrict__ xw_hi, unsigned short* __restrict__ xw_lo) {
    __shared__ unsigned short WS[2 * 8192];
    gemm_tile<HF, 1>(blockIdx.x, h, fc, nullptr, dis, nullptr, xw_hi, xw_lo, WS, NN);
}

// ---------------- agg+epilogue: one wave per node ----------------
// xws convention: xws = dis*xw, hi/lo split. Per-edge gather is hi-only, pure adds.
// msg = dis[n]*(sum_e xws_hi[c] + xws_hi[n]+xws_lo[n]) + conv_b
//       (self: dis[n]*xws[n] = dis^2*xw[n] = deg_inv*xw[n])
// v   = msg + relu(h[n]+root)*deg_inv[n]
// STEP 0: x = v + h[n]; LN(x)*gamma+beta; relu -> h[n] (in place)
// STEP 1: v -> out
template <int STEP>
__global__ void agg_ep(const int* __restrict__ row_start, const int* __restrict__ csr_col,
                       const float* __restrict__ dis, const float* __restrict__ deg_inv,
                       const unsigned short* __restrict__ xw_hi,
                       const unsigned short* __restrict__ xw_lo,
                       const float* __restrict__ conv_b, const float* __restrict__ root,
                       const float* __restrict__ gamma, const float* __restrict__ beta,
                       float* __restrict__ h, float* __restrict__ outp, int n) {
    int wid = (blockIdx.x * blockDim.x + threadIdx.x) >> 6;
    int lane = threadIdx.x & 63;
    if (wid >= n) return;
    int q = lane >> 4;
    int l16 = lane & 15;
    int s = row_start[wid];
    int e = row_start[wid + 1];
    float a0 = 0.f, a1 = 0.f, a2 = 0.f, a3 = 0.f, a4 = 0.f, a5 = 0.f, a6 = 0.f, a7 = 0.f;
    if (e - s <= 16) {
        int j0 = s + q;
        bool p0 = j0 < e, p1 = j0 + 4 < e, p2 = j0 + 8 < e, p3 = j0 + 12 < e;
        int c0 = p0 ? csr_col[j0] : 0;
        int c1 = p1 ? csr_col[j0 + 4] : 0;
        int c2 = p2 ? csr_col[j0 + 8] : 0;
        int c3 = p3 ? csr_col[j0 + 12] : 0;
        uint4 z = make_uint4(0, 0, 0, 0);
        uint4 g0 = z, g1 = z, g2 = z, g3 = z;
        if (p0) g0 = *reinterpret_cast<const uint4*>(&xw_hi[(size_t)c0 * HF + l16 * 8]);
        if (p1) g1 = *reinterpret_cast<const uint4*>(&xw_hi[(size_t)c1 * HF + l16 * 8]);
        if (p2) g2 = *reinterpret_cast<const uint4*>(&xw_hi[(size_t)c2 * HF + l16 * 8]);
        if (p3) g3 = *reinterpret_cast<const uint4*>(&xw_hi[(size_t)c3 * HF + l16 * 8]);
        a0 = (bf16lo_u32(g0.x) + bf16lo_u32(g1.x)) + (bf16lo_u32(g2.x) + bf16lo_u32(g3.x));
        a1 = (bf16hi_u32(g0.x) + bf16hi_u32(g1.x)) + (bf16hi_u32(g2.x) + bf16hi_u32(g3.x));
        a2 = (bf16lo_u32(g0.y) + bf16lo_u32(g1.y)) + (bf16lo_u32(g2.y) + bf16lo_u32(g3.y));
        a3 = (bf16hi_u32(g0.y) + bf16hi_u32(g1.y)) + (bf16hi_u32(g2.y) + bf16hi_u32(g3.y));
        a4 = (bf16lo_u32(g0.z) + bf16lo_u32(g1.z)) + (bf16lo_u32(g2.z) + bf16lo_u32(g3.z));
        a5 = (bf16hi_u32(g0.z) + bf16hi_u32(g1.z)) + (bf16hi_u32(g2.z) + bf16hi_u32(g3.z));
        a6 = (bf16lo_u32(g0.w) + bf16lo_u32(g1.w)) + (bf16lo_u32(g2.w) + bf16lo_u32(g3.w));
        a7 = (bf16hi_u32(g0.w) + bf16hi_u32(g1.w)) + (bf16hi_u32(g2.w) + bf16hi_u32(g3.w));
    } else {
        float b0 = 0.f, b1 = 0.f, b2 = 0.f, b3 = 0.f, b4 = 0.f, b5 = 0.f, b6 = 0.f, b7 = 0.f;
        int j = s + q;
        for (; j + 4 < e; j += 8) {
            int c0 = csr_col[j];
            int c1 = csr_col[j + 4];
            uint4 h0v = *reinterpret_cast<const uint4*>(&xw_hi[(size_t)c0 * HF + l16 * 8]);
            uint4 h1v = *reinterpret_cast<const uint4*>(&xw_hi[(size_t)c1 * HF + l16 * 8]);
            a0 += bf16lo_u32(h0v.x); a1 += bf16hi_u32(h0v.x);
            a2 += bf16lo_u32(h0v.y); a3 += bf16hi_u32(h0v.y);
            a4 += bf16lo_u32(h0v.z); a5 += bf16hi_u32(h0v.z);
            a6 += bf16lo_u32(h0v.w); a7 += bf16hi_u32(h0v.w);
            b0 += bf16lo_u32(h1v.x); b1 += bf16hi_u32(h1v.x);
            b2 += bf16lo_u32(h1v.y); b3 += bf16hi_u32(h1v.y);
            b4 += bf16lo_u32(h1v.z); b5 += bf16hi_u32(h1v.z);
            b6 += bf16lo_u32(h1v.w); b7 += bf16hi_u32(h1v.w);
        }
        if (j < e) {
            int c0 = csr_col[j];
            uint4 h0v = *reinterpret_cast<const uint4*>(&xw_hi[(size_t)c0 * HF + l16 * 8]);
            a0 += bf16lo_u32(h0v.x); a1 += bf16hi_u32(h0v.x);
            a2 += bf16lo_u32(h0v.y); a3 += bf16hi_u32(h0v.y);
            a4 += bf16lo_u32(h0v.z); a5 += bf16hi_u32(h0v.z);
            a6 += bf16lo_u32(h0v.w); a7 += bf16hi_u32(h0v.w);
        }
        a0 += b0; a1 += b1; a2 += b2; a3 += b3;
        a4 += b4; a5 += b5; a6 += b6; a7 += b7;
    }
#pragma unroll
    for (int m = 16; m < 64; m <<= 1) {
        a0 += __shfl_xor(a0, m, 64);
        a1 += __shfl_xor(a1, m, 64);
        a2 += __shfl_xor(a2, m, 64);
        a3 += __shfl_xor(a3, m, 64);
        a4 += __shfl_xor(a4, m, 64);
        a5 += __shfl_xor(a5, m, 64);
        a6 += __shfl_xor(a6, m, 64);
        a7 += __shfl_xor(a7, m, 64);
    }
    if (q != 0) return;
    float av[8] = {a0, a1, a2, a3, a4, a5, a6, a7};
    int f = l16 * 8;
    float dn = dis[wid];
    float di = deg_inv[wid];
    // self term: hi+lo reconstruct of xws[n] (dis*xw), added before the dn scale
    uint4 xh = *reinterpret_cast<const uint4*>(&xw_hi[(size_t)wid * HF + f]);
    uint4 xl = *reinterpret_cast<const uint4*>(&xw_lo[(size_t)wid * HF + f]);
    float sf[8];
    sf[0] = bf16lo_u32(xh.x) + bf16lo_u32(xl.x);
    sf[1] = bf16hi_u32(xh.x) + bf16hi_u32(xl.x);
    sf[2] = bf16lo_u32(xh.y) + bf16lo_u32(xl.y);
    sf[3] = bf16hi_u32(xh.y) + bf16hi_u32(xl.y);
    sf[4] = bf16lo_u32(xh.z) + bf16lo_u32(xl.z);
    sf[5] = bf16hi_u32(xh.z) + bf16hi_u32(xl.z);
    sf[6] = bf16lo_u32(xh.w) + bf16lo_u32(xl.w);
    sf[7] = bf16hi_u32(xh.w) + bf16hi_u32(xl.w);
    float4 hA = *reinterpret_cast<const float4*>(&h[(size_t)wid * HF + f]);
    float4 hB = *reinterpret_cast<const float4*>(&h[(size_t)wid * HF + f + 4]);
    float hv[8] = {hA.x, hA.y, hA.z, hA.w, hB.x, hB.y, hB.z, hB.w};
    float v[8];
#pragma unroll
    for (int k = 0; k < 8; ++k) {
        float msg = fmaf(dn, av[k] + sf[k], conv_b[f + k]);
        v[k] = msg + fmaxf(hv[k] + root[f + k], 0.f) * di;
    }
    if (STEP == 0) {
        float x[8];
        float ssum = 0.f;
#pragma unroll
        for (int k = 0; k < 8; ++k) { x[k] = v[k] + hv[k]; ssum += x[k]; }
#pragma unroll
        for (int m = 1; m < 16; m <<= 1) ssum += __shfl_xor(ssum, m, 64);
        float mu = ssum * (1.0f / HF);
        float var = 0.f;
#pragma unroll
        for (int k = 0; k < 8; ++k) { float d = x[k] - mu; var += d * d; }
#pragma unroll
        for (int m = 1; m < 16; m <<= 1) var += __shfl_xor(var, m, 64);
        float rs = rsqrtf(var * (1.0f / HF) + 1e-5f);
        float y[8];
#pragma unroll
        for (int k = 0; k < 8; ++k)
            y[k] = fmaxf((x[k] - mu) * rs * gamma[f + k] + beta[f + k], 0.f);
        *reinterpret_cast<float4*>(&h[(size_t)wid * HF + f]) =
            make_float4(y[0], y[1], y[2], y[3]);
        *reinterpret_cast<float4*>(&h[(size_t)wid * HF + f + 4]) =
            make_float4(y[4], y[5], y[6], y[7]);
    } else {
        *reinterpret_cast<float4*>(&outp[(size_t)wid * HF + f]) =
            make_float4(v[0], v[1], v[2], v[3]);
        *reinterpret_cast<float4*>(&outp[(size_t)wid * HF + f + 4]) =
            make_float4(v[4], v[5], v[6], v[7]);
    }
}

extern "C" void kernel_launch(void* const* d_in, const int* in_sizes, int n_in,
                              void* d_out, int out_size, void* d_ws, size_t ws_size,
                              hipStream_t stream) {
    const int N = NN, E = EE;
    const float* in_feat = (const float*)d_in[0];
    const int* row = (const int*)d_in[1];
    const int* col = (const int*)d_in[2];
    const float* lin_w = (const float*)d_in[3];
    const float* lin_b = (const float*)d_in[4];
    const float* conv_w = (const float*)d_in[5];
    const float* conv_b = (const float*)d_in[6];
    const float* root_emb = (const float*)d_in[7];
    const float* ln_gamma = (const float*)d_in[8];
    const float* ln_beta = (const float*)d_in[9];
    float* out = (float*)d_out;

    // workspace layout (4B units); all segments kept 16B-aligned
    float* ws = (float*)d_ws;
    size_t o = 0;
    float* deg_inv = ws + o; o += N;
    float* dis = ws + o; o += N;
    int* cnt8 = (int*)(ws + o); o += (size_t)NLB * N;   // 8-way privatized counters/bases
    int* row_start = (int*)(ws + o); o += N + 4;
    int* pos = (int*)(ws + o); o += E;
    int* bsum = (int*)(ws + o); o += 256;
    int* csr_col = (int*)(ws + o); o += E;
    unsigned short* fl = (unsigned short*)(ws + o); o += 32768;   // 128KB prepacked lin_w
    unsigned short* fc = (unsigned short*)(ws + o); o += 16384;   // 64KB prepacked conv_w
    float* h0 = ws + o; o += (size_t)N * HF;                      // h (updated in place)
    unsigned short* xw_hi = (unsigned short*)(ws + o); o += (size_t)N * HF / 2;
    unsigned short* xw_lo = (unsigned short*)(ws + o); o += (size_t)N * HF / 2;

    const int WB = (N + 3) / 4;   // 12500 agg blocks (4 waves each)

    // L1: zero cnt8 + prepack weights
    zero_prepack<<<256, 256, 0, stream>>>(lin_w, conv_w, fl, fc, cnt8);
    // L2: gemm0 (h0 = in_feat@lin_w^T + lin_b) ∥ privatized degree count
    gemm0_count<<<GBT + CEB, 256, 0, stream>>>(in_feat, fl, lin_b, h0, row, cnt8, pos);
    // L3a/b: scan -> row_start, per-label bases (in place in cnt8), deg_inv, dis
    scan_phase1<<<NBCH, 256, 0, stream>>>(cnt8, bsum, N);
    scan_phase3<<<NBCH, 256, 0, stream>>>(cnt8, bsum, row_start, deg_inv, dis, N, NBCH, E);
    // L4: xws0 = dis*(h0@conv_w^T) (hi/lo split) ∥ CSR fill (atomic-free, label bases)
    xw_fill<<<GBT + CEB, 256, 0, stream>>>(h0, fc, dis, xw_hi, xw_lo,
                                           row, col, cnt8, pos, csr_col);
    // L5: aggregate xws0 + step-0 epilogue -> h0 in place
    agg_ep<0><<<WB, 256, 0, stream>>>(row_start, csr_col, dis, deg_inv, xw_hi, xw_lo,
                                      conv_b, root_emb, ln_gamma + HF, ln_beta + HF,
                                      h0, nullptr, N);
    // L6: xws1 = dis*(h1@conv_w^T) (hi/lo split)
    xw_only<<<GBT, 256, 0, stream>>>(h0, fc, dis, xw_hi, xw_lo);
    // L7: aggregate xws1 + step-1 epilogue -> out
    agg_ep<1><<<WB, 256, 0, stream>>>(row_start, csr_col, dis, deg_inv, xw_hi, xw_lo,
                                      conv_b, root_emb, nullptr, nullptr,
                                      h0, out, N);
}

// Round 12
// 262.160 us; speedup vs baseline: 1.0124x; 1.0124x over previous
//
#include <hip/hip_runtime.h>
#include <stdint.h>

#define NN 50000
#define EE 600000
#define INF 256
#define HF 128
#define CEB ((EE + 255) / 256)    // 2344 edge blocks
#define GBT ((NN + 63) / 64)      // 782 gemm tiles
#define NBCH ((NN + 255) / 256)   // 196 scan chunks
#define NLB 8                     // count privatization labels (XCD count)

typedef __attribute__((ext_vector_type(8))) short short8;
typedef __attribute__((ext_vector_type(4))) float floatx4;

// ---------------- bf16 helpers ----------------
__device__ __forceinline__ unsigned short f32_to_bf16_rne(float x) {
    unsigned int u = __float_as_uint(x);
    unsigned int r = (u + 0x7FFFu + ((u >> 16) & 1u)) >> 16;
    return (unsigned short)r;
}
__device__ __forceinline__ float bf16_to_f32(unsigned short h) {
    return __uint_as_float(((unsigned int)h) << 16);
}
__device__ __forceinline__ float bf16lo_u32(unsigned int u) {
    return __uint_as_float(u << 16);
}
__device__ __forceinline__ float bf16hi_u32(unsigned int u) {
    return __uint_as_float(u & 0xFFFF0000u);
}
__device__ __forceinline__ void cvt_hilo8(float4 v0, float4 v1, short8& hs, short8& ls) {
    float x[8] = {v0.x, v0.y, v0.z, v0.w, v1.x, v1.y, v1.z, v1.w};
    union { short8 s; unsigned short u[8]; } H, L;
#pragma unroll
    for (int k = 0; k < 8; ++k) {
        unsigned short hi = f32_to_bf16_rne(x[k]);
        H.u[k] = hi;
        L.u[k] = f32_to_bf16_rne(x[k] - bf16_to_f32(hi));
    }
    hs = H.s;
    ls = L.s;
}

// ---------------- weight prepack: f32 -> hi/lo bf16 fragment-linear layout ----------
// linear order == LDS staging order, so GEMM staging is a pure 16B async copy.
__device__ __forceinline__ void prepack_one(int idx, const float* lw, const float* cw,
                                            unsigned short* fl, unsigned short* fc) {
    const float* src; unsigned short* dst; int K, c;
    if (idx < 8192) { src = lw; dst = fl; K = INF; c = idx; }
    else            { src = cw; dst = fc; K = HF; c = idx - 8192; }
    int lane = c & 63;
    int nt = (c >> 6) & 7;
    int hl = (c >> 9) & 1;
    int kc = c >> 10;
    int rw = nt * 16 + (lane & 15);
    int koff = kc * 32 + (lane >> 4) * 8;
    const float* p = &src[(size_t)rw * K + koff];
    float4 v0 = *reinterpret_cast<const float4*>(p);
    float4 v1 = *reinterpret_cast<const float4*>(p + 4);
    short8 hs, ls;
    cvt_hilo8(v0, v1, hs, ls);
    *reinterpret_cast<short8*>(&dst[(size_t)c * 8]) = hl ? ls : hs;
}

// ---------------- L1: zero cnt8 + prepack both weight matrices ----------------
__global__ void zero_prepack(const float* __restrict__ lw, const float* __restrict__ cw,
                             unsigned short* __restrict__ fl, unsigned short* __restrict__ fc,
                             int* __restrict__ cnt8) {
    int g = blockIdx.x * 256 + threadIdx.x;
    if (g < 12288) prepack_one(g, lw, cw, fl, fc);
    for (int i = g; i < NLB * NN; i += 256 * 256) cnt8[i] = 0;
}

// ---------------- scan phase1: per-chunk sums of deg (deg = sum over 8 labels) ------
__global__ void scan_phase1(const int* __restrict__ cnt8, int* __restrict__ bsum, int n) {
    __shared__ int sdata[256];
    int t = threadIdx.x;
    int i = blockIdx.x * 256 + t;
    int d = 0;
    if (i < n) {
#pragma unroll
        for (int k = 0; k < NLB; ++k) d += cnt8[(size_t)k * NN + i];
    }
    sdata[t] = d;
    __syncthreads();
    for (int s = 128; s > 0; s >>= 1) {
        if (t < s) sdata[t] += sdata[t + s];
        __syncthreads();
    }
    if (t == 0) bsum[blockIdx.x] = sdata[0];
}

// ---------------- scan phase2+3: row_start + per-label bases (in-place) + deg funcs --
__global__ void scan_phase3(int* __restrict__ cnt8, const int* __restrict__ bsum,
                            int* __restrict__ row_start,
                            float* __restrict__ deg_inv, float* __restrict__ dis,
                            int n, int nb, int E) {
    __shared__ int sb[256];
    __shared__ int sdata[256];
    int t = threadIdx.x;
    sb[t] = (t < nb) ? bsum[t] : 0;
    __syncthreads();
    for (int s = 1; s < 256; s <<= 1) {
        int add = (t >= s) ? sb[t - s] : 0;
        __syncthreads();
        sb[t] += add;
        __syncthreads();
    }
    int base = sb[blockIdx.x] - bsum[blockIdx.x];
    int i = blockIdx.x * 256 + t;
    int c8[NLB];
    int v = 0;
    if (i < n) {
#pragma unroll
        for (int k = 0; k < NLB; ++k) {
            c8[k] = cnt8[(size_t)k * NN + i];
            v += c8[k];
        }
    }
    sdata[t] = v;
    __syncthreads();
    for (int s = 1; s < 256; s <<= 1) {
        int add = (t >= s) ? sdata[t - s] : 0;
        __syncthreads();
        sdata[t] += add;
        __syncthreads();
    }
    if (i < n) {
        int rs = base + sdata[t] - v;
        row_start[i] = rs;
        int acc = rs;
#pragma unroll
        for (int k = 0; k < NLB; ++k) {   // rewrite counts -> per-label slot bases
            int cc = c8[k];
            cnt8[(size_t)k * NN + i] = acc;
            acc += cc;
        }
        float d = (float)(v + 1);
        deg_inv[i] = 1.0f / d;
        dis[i] = rsqrtf(d);
    }
    if (blockIdx.x == 0 && t == 0) row_start[n] = E;
}

// ---------------- split-bf16 MFMA GEMM tile; W staged by linear async copy ---------
// A always f32 (cvt in-loop).
// MODE 0: epilogue: +bias -> f32 C (h0 = in_feat@lin_w^T + lin_b)
// MODE 1/2: A == h. Epilogue computes, per node row n and col c (EXACT f32 xw):
//    xws_hi[n,c] = bf16(dis[n]*xw)                      (gather operand)
//    base[n,c]   = deg_inv[n]*xw + conv_b[c]
//                  + relu(h[n,c]+root[c])*deg_inv[n]
//                  + (MODE==1 ? h[n,c] : 0)             (step-0 residual folded in)
template <int K, int MODE>
__device__ __forceinline__ void gemm_tile(
    int bidx, const float* __restrict__ Af, const unsigned short* __restrict__ Wf,
    const float* __restrict__ bias, const float* __restrict__ Dis,
    const float* __restrict__ Dinv, const float* __restrict__ Root,
    float* __restrict__ Cf, unsigned short* __restrict__ Chi,
    unsigned short* WS, int M) {
    constexpr int NKC = K / 32;
    const int t = threadIdx.x;
    const int wave = t >> 6;
    const int lane = t & 63;
    const int lrow = lane & 15;
    const int quad = lane >> 4;
    const int bm = bidx * 64;
    int arow = bm + wave * 16 + lrow;
    if (arow >= M) arow = M - 1;   // clamp; stores are predicated

    floatx4 acc[8];
#pragma unroll
    for (int nt = 0; nt < 8; ++nt) acc[nt] = (floatx4){0.f, 0.f, 0.f, 0.f};

#pragma unroll
    for (int pp = 0; pp < NKC / 2; ++pp) {
        if (pp) __syncthreads();
        {
            const unsigned short* src = Wf + (size_t)pp * 16384 + (size_t)t * 8;
#if __has_builtin(__builtin_amdgcn_global_load_lds)
#pragma unroll
            for (int i = 0; i < 8; ++i) {
                __builtin_amdgcn_global_load_lds(
                    (const unsigned int*)(src + (size_t)i * 2048),
                    (unsigned int*)(WS + ((size_t)i * 256 + (t >> 6) * 64) * 8),
                    16, 0, 0);
            }
#else
            const uint4* s4 = reinterpret_cast<const uint4*>(Wf + (size_t)pp * 16384);
            uint4* d4 = reinterpret_cast<uint4*>(WS);
#pragma unroll
            for (int i = 0; i < 8; ++i) d4[t + 256 * i] = s4[t + 256 * i];
#endif
        }
        __syncthreads();
#pragma unroll
        for (int k2 = 0; k2 < 2; ++k2) {
            int kc = pp * 2 + k2;
            const float* ap = &Af[(size_t)arow * K + kc * 32 + quad * 8];
            float4 a0 = *reinterpret_cast<const float4*>(ap);
            float4 a1 = *reinterpret_cast<const float4*>(ap + 4);
            short8 afh, afl;
            cvt_hilo8(a0, a1, afh, afl);
            const unsigned short* wb = &WS[k2 * 8192 + lane * 8];
#pragma unroll
            for (int nt = 0; nt < 8; ++nt) {
                short8 bfh = *reinterpret_cast<const short8*>(wb + nt * 512);
                short8 bfl = *reinterpret_cast<const short8*>(wb + 4096 + nt * 512);
                acc[nt] = __builtin_amdgcn_mfma_f32_16x16x32_bf16(afh, bfh, acc[nt], 0, 0, 0);
                acc[nt] = __builtin_amdgcn_mfma_f32_16x16x32_bf16(afl, bfh, acc[nt], 0, 0, 0);
                acc[nt] = __builtin_amdgcn_mfma_f32_16x16x32_bf16(afh, bfl, acc[nt], 0, 0, 0);
            }
        }
    }

    float cb[8], rt[8];
#pragma unroll
    for (int nt = 0; nt < 8; ++nt) {
        int colh = nt * 16 + lrow;
        cb[nt] = bias[colh];
        if (MODE >= 1) rt[nt] = Root[colh];
    }

#pragma unroll
    for (int r = 0; r < 4; ++r) {
        int grow = bm + wave * 16 + quad * 4 + r;
        if (grow >= M) continue;
        if (MODE == 0) {
#pragma unroll
            for (int nt = 0; nt < 8; ++nt)
                Cf[(size_t)grow * HF + nt * 16 + lrow] = acc[nt][r] + cb[nt];
        } else {
            float dsr = Dis[grow];
            float di = Dinv[grow];
#pragma unroll
            for (int nt = 0; nt < 8; ++nt) {
                int colh = nt * 16 + lrow;
                float xw = acc[nt][r];
                float hvv = Af[(size_t)grow * HF + colh];   // A == h, L2-hot row
                float base = fmaf(di, xw, cb[nt]) +
                             fmaxf(hvv + rt[nt], 0.f) * di;
                if (MODE == 1) base += hvv;
                Cf[(size_t)grow * HF + colh] = base;
                Chi[(size_t)grow * HF + colh] = f32_to_bf16_rne(dsr * xw);
            }
        }
    }
}

// ---------------- L2: gemm0 ∥ privatized degree count ----------------
__global__ __launch_bounds__(256) void gemm0_count(
    const float* __restrict__ in_feat, const unsigned short* __restrict__ fl,
    const float* __restrict__ lin_b, float* __restrict__ h0,
    const int* __restrict__ row, int* __restrict__ cnt8, int* __restrict__ pos) {
    __shared__ unsigned short WS[2 * 8192];
    int b = blockIdx.x;
    if (b < GBT) {
        gemm_tile<INF, 0>(b, in_feat, fl, lin_b, nullptr, nullptr, nullptr,
                          h0, nullptr, WS, NN);
        return;
    }
    int eb = b - GBT;
    int e = eb * 256 + threadIdx.x;
    if (e < EE) pos[e] = atomicAdd(&cnt8[(size_t)(eb & 7) * NN + row[e]], 1);
}

// ---------------- L4: xw0 GEMM + base0/xws0 epilogue ∥ CSR fill ----------------
__global__ __launch_bounds__(256) void xw_fill(
    const float* __restrict__ h, const unsigned short* __restrict__ fc,
    const float* __restrict__ conv_b, const float* __restrict__ dis,
    const float* __restrict__ deg_inv, const float* __restrict__ root,
    float* __restrict__ base, unsigned short* __restrict__ xw_hi,
    const int* __restrict__ row, const int* __restrict__ col,
    const int* __restrict__ cnt8_base, const int* __restrict__ pos,
    int* __restrict__ csr_col) {
    __shared__ unsigned short WS[2 * 8192];
    int b = blockIdx.x;
    if (b < GBT) {
        gemm_tile<HF, 1>(b, h, fc, conv_b, dis, deg_inv, root, base, xw_hi, WS, NN);
        return;
    }
    int eb = b - GBT;
    int e = eb * 256 + threadIdx.x;
    if (e < EE) {
        int p = cnt8_base[(size_t)(eb & 7) * NN + row[e]] + pos[e];
        __builtin_nontemporal_store(col[e], &csr_col[p]);
    }
}

// ---------------- L6: xw1 GEMM + base1/xws1 epilogue (no residual) ----------------
__global__ __launch_bounds__(256) void xw_only(
    const float* __restrict__ h, const unsigned short* __restrict__ fc,
    const float* __restrict__ conv_b, const float* __restrict__ dis,
    const float* __restrict__ deg_inv, const float* __restrict__ root,
    float* __restrict__ base, unsigned short* __restrict__ xw_hi) {
    __shared__ unsigned short WS[2 * 8192];
    gemm_tile<HF, 2>(blockIdx.x, h, fc, conv_b, dis, deg_inv, root, base, xw_hi, WS, NN);
}

// ---------------- agg+epilogue: one wave per node ----------------
// x = dis[n]*sum_e xws_hi[c] + base[n]    (all per-node terms pre-folded in base)
// STEP 0: LN(x)*gamma+beta; relu -> h[n] (in place)
// STEP 1: x -> out
template <int STEP>
__global__ void agg_ep(const int* __restrict__ row_start, const int* __restrict__ csr_col,
                       const float* __restrict__ dis,
                       const unsigned short* __restrict__ xw_hi,
                       const float* __restrict__ base,
                       const float* __restrict__ gamma, const float* __restrict__ beta,
                       float* __restrict__ h, float* __restrict__ outp, int n) {
    int wid = (blockIdx.x * blockDim.x + threadIdx.x) >> 6;
    int lane = threadIdx.x & 63;
    if (wid >= n) return;
    int q = lane >> 4;
    int l16 = lane & 15;
    int s = row_start[wid];
    int e = row_start[wid + 1];
    float a0 = 0.f, a1 = 0.f, a2 = 0.f, a3 = 0.f, a4 = 0.f, a5 = 0.f, a6 = 0.f, a7 = 0.f;
    if (e - s <= 16) {
        int j0 = s + q;
        bool p0 = j0 < e, p1 = j0 + 4 < e, p2 = j0 + 8 < e, p3 = j0 + 12 < e;
        int c0 = p0 ? csr_col[j0] : 0;
        int c1 = p1 ? csr_col[j0 + 4] : 0;
        int c2 = p2 ? csr_col[j0 + 8] : 0;
        int c3 = p3 ? csr_col[j0 + 12] : 0;
        uint4 z = make_uint4(0, 0, 0, 0);
        uint4 g0 = z, g1 = z, g2 = z, g3 = z;
        if (p0) g0 = *reinterpret_cast<const uint4*>(&xw_hi[(size_t)c0 * HF + l16 * 8]);
        if (p1) g1 = *reinterpret_cast<const uint4*>(&xw_hi[(size_t)c1 * HF + l16 * 8]);
        if (p2) g2 = *reinterpret_cast<const uint4*>(&xw_hi[(size_t)c2 * HF + l16 * 8]);
        if (p3) g3 = *reinterpret_cast<const uint4*>(&xw_hi[(size_t)c3 * HF + l16 * 8]);
        a0 = (bf16lo_u32(g0.x) + bf16lo_u32(g1.x)) + (bf16lo_u32(g2.x) + bf16lo_u32(g3.x));
        a1 = (bf16hi_u32(g0.x) + bf16hi_u32(g1.x)) + (bf16hi_u32(g2.x) + bf16hi_u32(g3.x));
        a2 = (bf16lo_u32(g0.y) + bf16lo_u32(g1.y)) + (bf16lo_u32(g2.y) + bf16lo_u32(g3.y));
        a3 = (bf16hi_u32(g0.y) + bf16hi_u32(g1.y)) + (bf16hi_u32(g2.y) + bf16hi_u32(g3.y));
        a4 = (bf16lo_u32(g0.z) + bf16lo_u32(g1.z)) + (bf16lo_u32(g2.z) + bf16lo_u32(g3.z));
        a5 = (bf16hi_u32(g0.z) + bf16hi_u32(g1.z)) + (bf16hi_u32(g2.z) + bf16hi_u32(g3.z));
        a6 = (bf16lo_u32(g0.w) + bf16lo_u32(g1.w)) + (bf16lo_u32(g2.w) + bf16lo_u32(g3.w));
        a7 = (bf16hi_u32(g0.w) + bf16hi_u32(g1.w)) + (bf16hi_u32(g2.w) + bf16hi_u32(g3.w));
    } else {
        float b0 = 0.f, b1 = 0.f, b2 = 0.f, b3 = 0.f, b4 = 0.f, b5 = 0.f, b6 = 0.f, b7 = 0.f;
        int j = s + q;
        for (; j + 4 < e; j += 8) {
            int c0 = csr_col[j];
            int c1 = csr_col[j + 4];
            uint4 h0v = *reinterpret_cast<const uint4*>(&xw_hi[(size_t)c0 * HF + l16 * 8]);
            uint4 h1v = *reinterpret_cast<const uint4*>(&xw_hi[(size_t)c1 * HF + l16 * 8]);
            a0 += bf16lo_u32(h0v.x); a1 += bf16hi_u32(h0v.x);
            a2 += bf16lo_u32(h0v.y); a3 += bf16hi_u32(h0v.y);
            a4 += bf16lo_u32(h0v.z); a5 += bf16hi_u32(h0v.z);
            a6 += bf16lo_u32(h0v.w); a7 += bf16hi_u32(h0v.w);
            b0 += bf16lo_u32(h1v.x); b1 += bf16hi_u32(h1v.x);
            b2 += bf16lo_u32(h1v.y); b3 += bf16hi_u32(h1v.y);
            b4 += bf16lo_u32(h1v.z); b5 += bf16hi_u32(h1v.z);
            b6 += bf16lo_u32(h1v.w); b7 += bf16hi_u32(h1v.w);
        }
        if (j < e) {
            int c0 = csr_col[j];
            uint4 h0v = *reinterpret_cast<const uint4*>(&xw_hi[(size_t)c0 * HF + l16 * 8]);
            a0 += bf16lo_u32(h0v.x); a1 += bf16hi_u32(h0v.x);
            a2 += bf16lo_u32(h0v.y); a3 += bf16hi_u32(h0v.y);
            a4 += bf16lo_u32(h0v.z); a5 += bf16hi_u32(h0v.z);
            a6 += bf16lo_u32(h0v.w); a7 += bf16hi_u32(h0v.w);
        }
        a0 += b0; a1 += b1; a2 += b2; a3 += b3;
        a4 += b4; a5 += b5; a6 += b6; a7 += b7;
    }
#pragma unroll
    for (int m = 16; m < 64; m <<= 1) {
        a0 += __shfl_xor(a0, m, 64);
        a1 += __shfl_xor(a1, m, 64);
        a2 += __shfl_xor(a2, m, 64);
        a3 += __shfl_xor(a3, m, 64);
        a4 += __shfl_xor(a4, m, 64);
        a5 += __shfl_xor(a5, m, 64);
        a6 += __shfl_xor(a6, m, 64);
        a7 += __shfl_xor(a7, m, 64);
    }
    if (q != 0) return;
    float av[8] = {a0, a1, a2, a3, a4, a5, a6, a7};
    int f = l16 * 8;
    float dn = dis[wid];
    float4 bA = *reinterpret_cast<const float4*>(&base[(size_t)wid * HF + f]);
    float4 bB = *reinterpret_cast<const float4*>(&base[(size_t)wid * HF + f + 4]);
    float bv[8] = {bA.x, bA.y, bA.z, bA.w, bB.x, bB.y, bB.z, bB.w};
    float v[8];
#pragma unroll
    for (int k = 0; k < 8; ++k) v[k] = fmaf(dn, av[k], bv[k]);
    if (STEP == 0) {
        float ssum = 0.f;
#pragma unroll
        for (int k = 0; k < 8; ++k) ssum += v[k];
#pragma unroll
        for (int m = 1; m < 16; m <<= 1) ssum += __shfl_xor(ssum, m, 64);
        float mu = ssum * (1.0f / HF);
        float var = 0.f;
#pragma unroll
        for (int k = 0; k < 8; ++k) { float d = v[k] - mu; var += d * d; }
#pragma unroll
        for (int m = 1; m < 16; m <<= 1) var += __shfl_xor(var, m, 64);
        float rs = rsqrtf(var * (1.0f / HF) + 1e-5f);
        float y[8];
#pragma unroll
        for (int k = 0; k < 8; ++k)
            y[k] = fmaxf((v[k] - mu) * rs * gamma[f + k] + beta[f + k], 0.f);
        *reinterpret_cast<float4*>(&h[(size_t)wid * HF + f]) =
            make_float4(y[0], y[1], y[2], y[3]);
        *reinterpret_cast<float4*>(&h[(size_t)wid * HF + f + 4]) =
            make_float4(y[4], y[5], y[6], y[7]);
    } else {
        *reinterpret_cast<float4*>(&outp[(size_t)wid * HF + f]) =
            make_float4(v[0], v[1], v[2], v[3]);
        *reinterpret_cast<float4*>(&outp[(size_t)wid * HF + f + 4]) =
            make_float4(v[4], v[5], v[6], v[7]);
    }
}

extern "C" void kernel_launch(void* const* d_in, const int* in_sizes, int n_in,
                              void* d_out, int out_size, void* d_ws, size_t ws_size,
                              hipStream_t stream) {
    const int N = NN, E = EE;
    const float* in_feat = (const float*)d_in[0];
    const int* row = (const int*)d_in[1];
    const int* col = (const int*)d_in[2];
    const float* lin_w = (const float*)d_in[3];
    const float* lin_b = (const float*)d_in[4];
    const float* conv_w = (const float*)d_in[5];
    const float* conv_b = (const float*)d_in[6];
    const float* root_emb = (const float*)d_in[7];
    const float* ln_gamma = (const float*)d_in[8];
    const float* ln_beta = (const float*)d_in[9];
    float* out = (float*)d_out;

    // workspace layout (4B units); all segments kept 16B-aligned
    float* ws = (float*)d_ws;
    size_t o = 0;
    float* deg_inv = ws + o; o += N;
    float* dis = ws + o; o += N;
    int* cnt8 = (int*)(ws + o); o += (size_t)NLB * N;   // 8-way privatized counters/bases
    int* row_start = (int*)(ws + o); o += N + 4;
    int* pos = (int*)(ws + o); o += E;
    int* bsum = (int*)(ws + o); o += 256;
    int* csr_col = (int*)(ws + o); o += E;
    unsigned short* fl = (unsigned short*)(ws + o); o += 32768;   // 128KB prepacked lin_w
    unsigned short* fc = (unsigned short*)(ws + o); o += 16384;   // 64KB prepacked conv_w
    float* h0 = ws + o; o += (size_t)N * HF;                      // h (updated in place)
    float* basebuf = ws + o; o += (size_t)N * HF;                 // per-node epilogue base (f32)
    unsigned short* xw_hi = (unsigned short*)(ws + o); o += (size_t)N * HF / 2;

    const int WB = (N + 3) / 4;   // 12500 agg blocks (4 waves each)

    // L1: zero cnt8 + prepack weights
    zero_prepack<<<256, 256, 0, stream>>>(lin_w, conv_w, fl, fc, cnt8);
    // L2: gemm0 (h0 = in_feat@lin_w^T + lin_b) ∥ privatized degree count
    gemm0_count<<<GBT + CEB, 256, 0, stream>>>(in_feat, fl, lin_b, h0, row, cnt8, pos);
    // L3a/b: scan -> row_start, per-label bases (in place in cnt8), deg_inv, dis
    scan_phase1<<<NBCH, 256, 0, stream>>>(cnt8, bsum, N);
    scan_phase3<<<NBCH, 256, 0, stream>>>(cnt8, bsum, row_start, deg_inv, dis, N, NBCH, E);
    // L4: xw0 GEMM + base0/xws0 epilogue ∥ CSR fill (atomic-free, label bases)
    xw_fill<<<GBT + CEB, 256, 0, stream>>>(h0, fc, conv_b, dis, deg_inv, root_emb,
                                           basebuf, xw_hi,
                                           row, col, cnt8, pos, csr_col);
    // L5: aggregate xws0 + LN/ReLU -> h0 in place
    agg_ep<0><<<WB, 256, 0, stream>>>(row_start, csr_col, dis, xw_hi, basebuf,
                                      ln_gamma + HF, ln_beta + HF, h0, nullptr, N);
    // L6: xw1 GEMM + base1/xws1 epilogue (no residual)
    xw_only<<<GBT, 256, 0, stream>>>(h0, fc, conv_b, dis, deg_inv, root_emb,
                                     basebuf, xw_hi);
    // L7: aggregate xws1 -> out
    agg_ep<1><<<WB, 256, 0, stream>>>(row_start, csr_col, dis, xw_hi, basebuf,
                                      nullptr, nullptr, nullptr, out, N);
}